// Round 1
// baseline (281.514 us; speedup 1.0000x reference)
//
#include <hip/hip_runtime.h>
#include <math.h>

#define EE 5120
#define DD 2560
#define BB 32

// ---------------------------------------------------------------------------
// K0: transpose x (B,D) -> xT (D,B) so GEMM kernels can read activation rows
// as contiguous wave-uniform scalar loads. Also zeroes the dbc accumulator.
__global__ __launch_bounds__(256) void k0_prep(const float* __restrict__ x,
                                               float* __restrict__ xT,
                                               float* __restrict__ dbc) {
  int g = blockIdx.x * 256 + threadIdx.x;
  if (g < BB * DD) {
    int b = g / DD, k = g % DD;
    xT[k * BB + b] = x[g];     // scattered write, 0.33 MB, L2-absorbed
  }
  if (g < BB * 192) dbc[g] = 0.f;
}

// ---------------------------------------------------------------------------
// K1a: fused GEMM for x@W_in_ssm and x@W_in_mlp.
// Column space C = 10240 (0..5119 ssm, 5120..10239 mlp).
// grid = 1280 blocks (5/CU exact): 160 col-blocks x 8 outer k-splits.
// block = 256 = 64 lanes (cols) x 4 inner k-slices; k-len 80 per thread.
// Each thread: 32-row fp32 accumulator; weights fetched once; x via scalar
// loads from xT. In-block LDS reduce over the 4 k-slices (padded, 2-phase),
// cross-block partials P1[so][b][c] reduced in K1b.
__global__ __launch_bounds__(256) void k1a_gemm_in(const float* __restrict__ Wssm,
                                                   const float* __restrict__ Wmlp,
                                                   const float* __restrict__ xT,
                                                   float* __restrict__ P1) {
  const int bid  = blockIdx.x;
  const int cb   = bid % 160;
  const int so   = bid / 160;                 // 0..7
  const int lane = threadIdx.x & 63;
  const int ks   = __builtin_amdgcn_readfirstlane((int)(threadIdx.x >> 6));
  const int c    = cb * 64 + lane;            // 0..10239 (uniform mat per block)
  const float* __restrict__ W = (c < EE) ? Wssm : Wmlp;
  const int e  = (c < EE) ? c : c - EE;
  const int k0 = so * 320 + ks * 80;

  float acc[BB];
#pragma unroll
  for (int b = 0; b < BB; ++b) acc[b] = 0.f;

  const float* __restrict__ wp = W + (size_t)k0 * EE + e;
  const float* __restrict__ xp = xT + k0 * BB;
#pragma unroll 2
  for (int kk = 0; kk < 80; ++kk) {
    float w = wp[(size_t)kk * EE];
#pragma unroll
    for (int b = 0; b < BB; ++b) acc[b] = fmaf(xp[kk * BB + b], w, acc[b]);
  }

  // two-phase LDS reduce over ks (17-float stride: conflict-free)
  __shared__ float red[4][64][17];
  const int ksid = threadIdx.x >> 6;
#pragma unroll
  for (int half = 0; half < 2; ++half) {
    __syncthreads();
#pragma unroll
    for (int i = 0; i < 16; ++i) red[ksid][lane][i] = acc[half * 16 + i];
    __syncthreads();
#pragma unroll
    for (int j = 0; j < 4; ++j) {
      int bi = ksid * 4 + j;
      float v = red[0][lane][bi] + red[1][lane][bi] +
                red[2][lane][bi] + red[3][lane][bi];
      int b = half * 16 + bi;
      P1[((size_t)(so * BB + b)) * 10240 + c] = v;
    }
  }
}

// ---------------------------------------------------------------------------
// K1b: reduce the 8 outer partials, fuse conv(4-tap)+silu -> xt, silu -> res.
__global__ __launch_bounds__(256) void k1b_epilogue(const float* __restrict__ P1,
                                                    const float* __restrict__ cs,
                                                    const float* __restrict__ cw,
                                                    const float* __restrict__ cbv,
                                                    float* __restrict__ xt,
                                                    float* __restrict__ res) {
  int g = blockIdx.x * 256 + threadIdx.x;     // 0..163839
  int e = g % EE;
  int b = g / EE;
  float xs = 0.f, xm = 0.f;
#pragma unroll
  for (int so = 0; so < 8; ++so) {
    xs += P1[((size_t)(so * BB + b)) * 10240 + e];
    xm += P1[((size_t)(so * BB + b)) * 10240 + EE + e];
  }
  size_t be = (size_t)b * EE + e;
  const size_t T = (size_t)BB * EE;
  float conv = cs[be] * cw[be] + cs[T + be] * cw[T + be] +
               cs[2 * T + be] * cw[2 * T + be] + xs * cw[3 * T + be] + cbv[be];
  float sig = 1.f / (1.f + expf(-conv));
  xt[be] = conv * sig;
  float sm = 1.f / (1.f + expf(-xm));
  res[be] = xm * sm;
}

// ---------------------------------------------------------------------------
// K2: dbc = xt @ Wx  (32 x 5120 x 192). grid = 96 blocks = 3 col-blocks x 32
// outer k-splits; block = 64 lanes x 4 inner k-slices (k-len 40). In-block LDS
// reduce, then atomicAdd into zeroed dbc (32-way contention per address).
__global__ __launch_bounds__(256) void k2_dbc(const float* __restrict__ xt,
                                              const float* __restrict__ Wx,
                                              float* __restrict__ dbc) {
  const int bid  = blockIdx.x;
  const int cbi  = bid % 3;
  const int so   = bid / 3;                   // 0..31
  const int lane = threadIdx.x & 63;
  const int ks   = __builtin_amdgcn_readfirstlane((int)(threadIdx.x >> 6));
  const int j    = cbi * 64 + lane;           // 0..191
  const int k0   = so * 160 + ks * 40;

  float acc[BB];
#pragma unroll
  for (int b = 0; b < BB; ++b) acc[b] = 0.f;

  for (int kk = 0; kk < 40; ++kk) {
    int k = k0 + kk;
    float w = Wx[(size_t)k * 192 + j];
#pragma unroll
    for (int b = 0; b < BB; ++b)
      acc[b] = fmaf(xt[(size_t)b * EE + k], w, acc[b]);
  }

  __shared__ float red[4][64][17];
  const int ksid = threadIdx.x >> 6;
#pragma unroll
  for (int half = 0; half < 2; ++half) {
    __syncthreads();
#pragma unroll
    for (int i = 0; i < 16; ++i) red[ksid][lane][i] = acc[half * 16 + i];
    __syncthreads();
#pragma unroll
    for (int jj = 0; jj < 4; ++jj) {
      int bi = ksid * 4 + jj;
      float v = red[0][lane][bi] + red[1][lane][bi] +
                red[2][lane][bi] + red[3][lane][bi];
      int b = half * 16 + bi;
      atomicAdd(&dbc[b * 192 + j], v);
    }
  }
}

// ---------------------------------------------------------------------------
// K3: dt-GEMM (K=160) + softplus + SSM step + D*xt + residual multiply.
// grid = 320 blocks = 80 e-blocks x 4 b-groups; block = 64 lanes x 4 subs;
// each thread handles 2 batch rows for one column e. Writes zT (E,B) for K4's
// scalar loads.
__global__ __launch_bounds__(256) void k3_ssm(const float* __restrict__ dbc,
                                              const float* __restrict__ Wdt,
                                              const float* __restrict__ dt_bias,
                                              const float* __restrict__ A_log,
                                              const float* __restrict__ Dvec,
                                              const float* __restrict__ h,
                                              const float* __restrict__ xt,
                                              const float* __restrict__ res,
                                              float* __restrict__ zT) {
  const int eb   = blockIdx.x % 80;
  const int bg   = blockIdx.x / 80;           // 0..3
  const int lane = threadIdx.x & 63;
  const int sub  = __builtin_amdgcn_readfirstlane((int)(threadIdx.x >> 6));
  const int e    = eb * 64 + lane;
  const int bq   = bg * 4 + sub;              // 0..15
  const int b0   = bq * 2, b1 = b0 + 1;

  float a0 = 0.f, a1 = 0.f;
  const float* __restrict__ d0 = dbc + b0 * 192;
  const float* __restrict__ d1 = dbc + b1 * 192;
#pragma unroll 4
  for (int r = 0; r < 160; ++r) {
    float w = Wdt[(size_t)r * EE + e];
    a0 = fmaf(d0[r], w, a0);
    a1 = fmaf(d1[r], w, a1);
  }

  float An[16];
#pragma unroll
  for (int n = 0; n < 16; ++n) An[n] = -expf(A_log[e * 16 + n]);
  const float bias = dt_bias[e];
  const float Dv = Dvec[e];

#pragma unroll
  for (int t = 0; t < 2; ++t) {
    int b = t ? b1 : b0;
    float a = t ? a1 : a0;
    float v = a + bias;
    float dt = (v > 20.f) ? v : log1pf(expf(v));
    size_t be = (size_t)b * EE + e;
    float xb = xt[be];
    const float* __restrict__ hb = h + be * 16;
    const float* __restrict__ Bm = dbc + b * 192 + 160;
    const float* __restrict__ Cm = dbc + b * 192 + 176;
    float y = 0.f;
#pragma unroll
    for (int n = 0; n < 16; ++n) {
      float dA = expf(dt * An[n]);
      float hn = fmaf(hb[n], dA, dt * Bm[n] * xb);
      y = fmaf(hn, Cm[n], y);
    }
    y = fmaf(Dv, xb, y);
    zT[e * BB + b] = y * res[be];
  }
}

// ---------------------------------------------------------------------------
// K4a: out-GEMM partials: (y*res) @ W_out  (32 x 5120 x 2560).
// grid = 640 blocks = 40 col-blocks x 16 outer k-splits; block = 64 lanes x 4
// inner slices (k-len 80). Partials P4[so][b][d] reduced in K4b.
__global__ __launch_bounds__(256) void k4a_gemm_out(const float* __restrict__ Wout,
                                                    const float* __restrict__ zT,
                                                    float* __restrict__ P4) {
  const int bid  = blockIdx.x;
  const int cb   = bid % 40;
  const int so   = bid / 40;                  // 0..15
  const int lane = threadIdx.x & 63;
  const int ks   = __builtin_amdgcn_readfirstlane((int)(threadIdx.x >> 6));
  const int d    = cb * 64 + lane;
  const int k0   = so * 320 + ks * 80;

  float acc[BB];
#pragma unroll
  for (int b = 0; b < BB; ++b) acc[b] = 0.f;

  const float* __restrict__ wp = Wout + (size_t)k0 * DD + d;
  const float* __restrict__ xp = zT + k0 * BB;
#pragma unroll 2
  for (int kk = 0; kk < 80; ++kk) {
    float w = wp[(size_t)kk * DD];
#pragma unroll
    for (int b = 0; b < BB; ++b) acc[b] = fmaf(xp[kk * BB + b], w, acc[b]);
  }

  __shared__ float red[4][64][17];
  const int ksid = threadIdx.x >> 6;
#pragma unroll
  for (int half = 0; half < 2; ++half) {
    __syncthreads();
#pragma unroll
    for (int i = 0; i < 16; ++i) red[ksid][lane][i] = acc[half * 16 + i];
    __syncthreads();
#pragma unroll
    for (int j = 0; j < 4; ++j) {
      int bi = ksid * 4 + j;
      float v = red[0][lane][bi] + red[1][lane][bi] +
                red[2][lane][bi] + red[3][lane][bi];
      int b = half * 16 + bi;
      P4[((size_t)(so * BB + b)) * DD + d] = v;
    }
  }
}

// K4b: reduce 16 partials -> final output (B, D) flat.
__global__ __launch_bounds__(256) void k4b_reduce(const float* __restrict__ P4,
                                                  float* __restrict__ out) {
  int g = blockIdx.x * 256 + threadIdx.x;     // 0..81919 == b*DD + d
  int d = g % DD;
  int b = g / DD;
  float s = 0.f;
#pragma unroll
  for (int so = 0; so < 16; ++so) s += P4[((size_t)(so * BB + b)) * DD + d];
  out[g] = s;
}

// ---------------------------------------------------------------------------
extern "C" void kernel_launch(void* const* d_in, const int* in_sizes, int n_in,
                              void* d_out, int out_size, void* d_ws, size_t ws_size,
                              hipStream_t stream) {
  const float* x       = (const float*)d_in[0];
  const float* Wssm    = (const float*)d_in[1];
  const float* Wmlp    = (const float*)d_in[2];
  const float* Wout    = (const float*)d_in[3];
  const float* conv_w  = (const float*)d_in[4];
  const float* conv_b  = (const float*)d_in[5];
  const float* conv_st = (const float*)d_in[6];
  const float* Wx      = (const float*)d_in[7];
  const float* Wdt     = (const float*)d_in[8];
  const float* dt_bias = (const float*)d_in[9];
  const float* A_log   = (const float*)d_in[10];
  const float* Dvec    = (const float*)d_in[11];
  const float* h       = (const float*)d_in[12];
  float* out = (float*)d_out;

  float* ws = (float*)d_ws;
  float* xT  = ws;                       // 81,920
  float* P1  = xT  + 81920;              // 2,621,440
  float* xt  = P1  + 2621440;            // 163,840
  float* res = xt  + 163840;             // 163,840
  float* dbc = res + 163840;             // 6,144
  float* zT  = dbc + 6144;               // 163,840
  float* P4  = zT  + 163840;             // 1,310,720  (total ~18.05 MB)

  hipLaunchKernelGGL(k0_prep,     dim3(320),  dim3(256), 0, stream, x, xT, dbc);
  hipLaunchKernelGGL(k1a_gemm_in, dim3(1280), dim3(256), 0, stream, Wssm, Wmlp, xT, P1);
  hipLaunchKernelGGL(k1b_epilogue,dim3(640),  dim3(256), 0, stream, P1, conv_st, conv_w, conv_b, xt, res);
  hipLaunchKernelGGL(k2_dbc,      dim3(96),   dim3(256), 0, stream, xt, Wx, dbc);
  hipLaunchKernelGGL(k3_ssm,      dim3(320),  dim3(256), 0, stream, dbc, Wdt, dt_bias, A_log, Dvec, h, xt, res, zT);
  hipLaunchKernelGGL(k4a_gemm_out,dim3(640),  dim3(256), 0, stream, Wout, zT, P4);
  hipLaunchKernelGGL(k4b_reduce,  dim3(320),  dim3(256), 0, stream, P4, out);
}

// Round 2
// 279.796 us; speedup vs baseline: 1.0061x; 1.0061x over previous
//
#include <hip/hip_runtime.h>
#include <math.h>

#define EE 5120
#define DD 2560
#define BB 32

// ---------------------------------------------------------------------------
// K0: transpose x (B,D) -> xT (D,B) so GEMM kernels can read activation rows
// as contiguous wave-uniform scalar loads. Also zeroes the dbc accumulator.
__global__ __launch_bounds__(256) void k0_prep(const float* __restrict__ x,
                                               float* __restrict__ xT,
                                               float* __restrict__ dbc) {
  int g = blockIdx.x * 256 + threadIdx.x;
  if (g < BB * DD) {
    int b = g / DD, k = g % DD;
    xT[k * BB + b] = x[g];     // scattered write, 0.33 MB, L2-absorbed
  }
  if (g < BB * 192) dbc[g] = 0.f;
}

// ---------------------------------------------------------------------------
// K1a: fused GEMM for x@W_in_ssm and x@W_in_mlp.
// Column space C = 10240 (0..5119 ssm, 5120..10239 mlp).
// grid = 1280 blocks (5/CU exact): 160 col-blocks x 8 outer k-splits.
// block = 256 = 64 lanes (cols) x 4 inner k-slices; k-len 80 per thread.
// Round-2 change: explicit 4-deep weight prefetch per batch — 4 independent
// global loads in flight before the 4 FMA slabs, breaking the 1-load-latency-
// per-iteration serialization seen in round 1 (VALUBusy 23%, 1.3 TB/s).
__global__ __launch_bounds__(256) void k1a_gemm_in(const float* __restrict__ Wssm,
                                                   const float* __restrict__ Wmlp,
                                                   const float* __restrict__ xT,
                                                   float* __restrict__ P1) {
  const int bid  = blockIdx.x;
  const int cb   = bid % 160;
  const int so   = bid / 160;                 // 0..7
  const int lane = threadIdx.x & 63;
  const int ks   = __builtin_amdgcn_readfirstlane((int)(threadIdx.x >> 6));
  const int c    = cb * 64 + lane;            // 0..10239 (uniform mat per block)
  const float* __restrict__ W = (c < EE) ? Wssm : Wmlp;
  const int e  = (c < EE) ? c : c - EE;
  const int k0 = so * 320 + ks * 80;

  float acc[BB];
#pragma unroll
  for (int b = 0; b < BB; ++b) acc[b] = 0.f;

  const float* __restrict__ wp = W + (size_t)k0 * EE + e;
  const float* __restrict__ xp = xT + k0 * BB;
  for (int kk = 0; kk < 80; kk += 4) {
    float w0 = wp[(size_t)(kk + 0) * EE];
    float w1 = wp[(size_t)(kk + 1) * EE];
    float w2 = wp[(size_t)(kk + 2) * EE];
    float w3 = wp[(size_t)(kk + 3) * EE];
#pragma unroll
    for (int b = 0; b < BB; ++b) acc[b] = fmaf(xp[(kk + 0) * BB + b], w0, acc[b]);
#pragma unroll
    for (int b = 0; b < BB; ++b) acc[b] = fmaf(xp[(kk + 1) * BB + b], w1, acc[b]);
#pragma unroll
    for (int b = 0; b < BB; ++b) acc[b] = fmaf(xp[(kk + 2) * BB + b], w2, acc[b]);
#pragma unroll
    for (int b = 0; b < BB; ++b) acc[b] = fmaf(xp[(kk + 3) * BB + b], w3, acc[b]);
  }

  // two-phase LDS reduce over ks (17-float stride: conflict-free)
  __shared__ float red[4][64][17];
  const int ksid = threadIdx.x >> 6;
#pragma unroll
  for (int half = 0; half < 2; ++half) {
    __syncthreads();
#pragma unroll
    for (int i = 0; i < 16; ++i) red[ksid][lane][i] = acc[half * 16 + i];
    __syncthreads();
#pragma unroll
    for (int j = 0; j < 4; ++j) {
      int bi = ksid * 4 + j;
      float v = red[0][lane][bi] + red[1][lane][bi] +
                red[2][lane][bi] + red[3][lane][bi];
      int b = half * 16 + bi;
      P1[((size_t)(so * BB + b)) * 10240 + c] = v;
    }
  }
}

// ---------------------------------------------------------------------------
// K1b: reduce the 8 outer partials, fuse conv(4-tap)+silu -> xt, silu -> res.
__global__ __launch_bounds__(256) void k1b_epilogue(const float* __restrict__ P1,
                                                    const float* __restrict__ cs,
                                                    const float* __restrict__ cw,
                                                    const float* __restrict__ cbv,
                                                    float* __restrict__ xt,
                                                    float* __restrict__ res) {
  int g = blockIdx.x * 256 + threadIdx.x;     // 0..163839
  int e = g % EE;
  int b = g / EE;
  float xs = 0.f, xm = 0.f;
#pragma unroll
  for (int so = 0; so < 8; ++so) {
    xs += P1[((size_t)(so * BB + b)) * 10240 + e];
    xm += P1[((size_t)(so * BB + b)) * 10240 + EE + e];
  }
  size_t be = (size_t)b * EE + e;
  const size_t T = (size_t)BB * EE;
  float conv = cs[be] * cw[be] + cs[T + be] * cw[T + be] +
               cs[2 * T + be] * cw[2 * T + be] + xs * cw[3 * T + be] + cbv[be];
  float sig = 1.f / (1.f + expf(-conv));
  xt[be] = conv * sig;
  float sm = 1.f / (1.f + expf(-xm));
  res[be] = xm * sm;
}

// ---------------------------------------------------------------------------
// K2: dbc = xt @ Wx  (32 x 5120 x 192). grid = 192 blocks = 3 col-blocks x 64
// outer k-splits; block = 64 lanes x 4 inner k-slices (k-len 20, prefetch-4).
// In-block LDS reduce, then atomicAdd into zeroed dbc (64-way contention).
__global__ __launch_bounds__(256) void k2_dbc(const float* __restrict__ xt,
                                              const float* __restrict__ Wx,
                                              float* __restrict__ dbc) {
  const int bid  = blockIdx.x;
  const int cbi  = bid % 3;
  const int so   = bid / 3;                   // 0..63
  const int lane = threadIdx.x & 63;
  const int j    = cbi * 64 + lane;           // 0..191
  const int k0   = so * 80 + (int)(threadIdx.x >> 6) * 20;

  float acc[BB];
#pragma unroll
  for (int b = 0; b < BB; ++b) acc[b] = 0.f;

  for (int kk = 0; kk < 20; kk += 4) {
    int k = k0 + kk;
    float w0 = Wx[(size_t)(k + 0) * 192 + j];
    float w1 = Wx[(size_t)(k + 1) * 192 + j];
    float w2 = Wx[(size_t)(k + 2) * 192 + j];
    float w3 = Wx[(size_t)(k + 3) * 192 + j];
#pragma unroll
    for (int b = 0; b < BB; ++b) acc[b] = fmaf(xt[(size_t)b * EE + k + 0], w0, acc[b]);
#pragma unroll
    for (int b = 0; b < BB; ++b) acc[b] = fmaf(xt[(size_t)b * EE + k + 1], w1, acc[b]);
#pragma unroll
    for (int b = 0; b < BB; ++b) acc[b] = fmaf(xt[(size_t)b * EE + k + 2], w2, acc[b]);
#pragma unroll
    for (int b = 0; b < BB; ++b) acc[b] = fmaf(xt[(size_t)b * EE + k + 3], w3, acc[b]);
  }

  __shared__ float red[4][64][17];
  const int ksid = threadIdx.x >> 6;
#pragma unroll
  for (int half = 0; half < 2; ++half) {
    __syncthreads();
#pragma unroll
    for (int i = 0; i < 16; ++i) red[ksid][lane][i] = acc[half * 16 + i];
    __syncthreads();
#pragma unroll
    for (int jj = 0; jj < 4; ++jj) {
      int bi = ksid * 4 + jj;
      float v = red[0][lane][bi] + red[1][lane][bi] +
                red[2][lane][bi] + red[3][lane][bi];
      int b = half * 16 + bi;
      atomicAdd(&dbc[b * 192 + j], v);
    }
  }
}

// ---------------------------------------------------------------------------
// K3: dt-GEMM (K=160, prefetch-4) + softplus + SSM step + D*xt + residual mul.
// grid = 320 blocks = 80 e-blocks x 4 b-groups; block = 64 lanes x 4 subs;
// each thread handles 2 batch rows for one column e. Writes zT (E,B).
__global__ __launch_bounds__(256) void k3_ssm(const float* __restrict__ dbc,
                                              const float* __restrict__ Wdt,
                                              const float* __restrict__ dt_bias,
                                              const float* __restrict__ A_log,
                                              const float* __restrict__ Dvec,
                                              const float* __restrict__ h,
                                              const float* __restrict__ xt,
                                              const float* __restrict__ res,
                                              float* __restrict__ zT) {
  const int eb   = blockIdx.x % 80;
  const int bg   = blockIdx.x / 80;           // 0..3
  const int lane = threadIdx.x & 63;
  const int sub  = __builtin_amdgcn_readfirstlane((int)(threadIdx.x >> 6));
  const int e    = eb * 64 + lane;
  const int bq   = bg * 4 + sub;              // 0..15
  const int b0   = bq * 2, b1 = b0 + 1;

  float a0 = 0.f, a1 = 0.f;
  const float* __restrict__ d0 = dbc + b0 * 192;
  const float* __restrict__ d1 = dbc + b1 * 192;
  for (int r = 0; r < 160; r += 4) {
    float w0 = Wdt[(size_t)(r + 0) * EE + e];
    float w1 = Wdt[(size_t)(r + 1) * EE + e];
    float w2 = Wdt[(size_t)(r + 2) * EE + e];
    float w3 = Wdt[(size_t)(r + 3) * EE + e];
    a0 = fmaf(d0[r + 0], w0, a0);  a1 = fmaf(d1[r + 0], w0, a1);
    a0 = fmaf(d0[r + 1], w1, a0);  a1 = fmaf(d1[r + 1], w1, a1);
    a0 = fmaf(d0[r + 2], w2, a0);  a1 = fmaf(d1[r + 2], w2, a1);
    a0 = fmaf(d0[r + 3], w3, a0);  a1 = fmaf(d1[r + 3], w3, a1);
  }

  float An[16];
#pragma unroll
  for (int n = 0; n < 16; ++n) An[n] = -expf(A_log[e * 16 + n]);
  const float bias = dt_bias[e];
  const float Dv = Dvec[e];

#pragma unroll
  for (int t = 0; t < 2; ++t) {
    int b = t ? b1 : b0;
    float a = t ? a1 : a0;
    float v = a + bias;
    float dt = (v > 20.f) ? v : log1pf(expf(v));
    size_t be = (size_t)b * EE + e;
    float xb = xt[be];
    const float* __restrict__ hb = h + be * 16;
    const float* __restrict__ Bm = dbc + b * 192 + 160;
    const float* __restrict__ Cm = dbc + b * 192 + 176;
    float y = 0.f;
#pragma unroll
    for (int n = 0; n < 16; ++n) {
      float dA = expf(dt * An[n]);
      float hn = fmaf(hb[n], dA, dt * Bm[n] * xb);
      y = fmaf(hn, Cm[n], y);
    }
    y = fmaf(Dv, xb, y);
    zT[e * BB + b] = y * res[be];
  }
}

// ---------------------------------------------------------------------------
// K4a: out-GEMM partials: (y*res) @ W_out  (32 x 5120 x 2560).
// grid = 640 blocks = 40 col-blocks x 16 outer k-splits; block = 64 lanes x 4
// inner slices (k-len 80, prefetch-4). Partials P4[so][b][d] reduced in K4b.
__global__ __launch_bounds__(256) void k4a_gemm_out(const float* __restrict__ Wout,
                                                    const float* __restrict__ zT,
                                                    float* __restrict__ P4) {
  const int bid  = blockIdx.x;
  const int cb   = bid % 40;
  const int so   = bid / 40;                  // 0..15
  const int lane = threadIdx.x & 63;
  const int ks   = __builtin_amdgcn_readfirstlane((int)(threadIdx.x >> 6));
  const int d    = cb * 64 + lane;
  const int k0   = so * 320 + ks * 80;

  float acc[BB];
#pragma unroll
  for (int b = 0; b < BB; ++b) acc[b] = 0.f;

  const float* __restrict__ wp = Wout + (size_t)k0 * DD + d;
  const float* __restrict__ xp = zT + k0 * BB;
  for (int kk = 0; kk < 80; kk += 4) {
    float w0 = wp[(size_t)(kk + 0) * DD];
    float w1 = wp[(size_t)(kk + 1) * DD];
    float w2 = wp[(size_t)(kk + 2) * DD];
    float w3 = wp[(size_t)(kk + 3) * DD];
#pragma unroll
    for (int b = 0; b < BB; ++b) acc[b] = fmaf(xp[(kk + 0) * BB + b], w0, acc[b]);
#pragma unroll
    for (int b = 0; b < BB; ++b) acc[b] = fmaf(xp[(kk + 1) * BB + b], w1, acc[b]);
#pragma unroll
    for (int b = 0; b < BB; ++b) acc[b] = fmaf(xp[(kk + 2) * BB + b], w2, acc[b]);
#pragma unroll
    for (int b = 0; b < BB; ++b) acc[b] = fmaf(xp[(kk + 3) * BB + b], w3, acc[b]);
  }

  __shared__ float red[4][64][17];
  const int ksid = threadIdx.x >> 6;
#pragma unroll
  for (int half = 0; half < 2; ++half) {
    __syncthreads();
#pragma unroll
    for (int i = 0; i < 16; ++i) red[ksid][lane][i] = acc[half * 16 + i];
    __syncthreads();
#pragma unroll
    for (int j = 0; j < 4; ++j) {
      int bi = ksid * 4 + j;
      float v = red[0][lane][bi] + red[1][lane][bi] +
                red[2][lane][bi] + red[3][lane][bi];
      int b = half * 16 + bi;
      P4[((size_t)(so * BB + b)) * DD + d] = v;
    }
  }
}

// K4b: reduce 16 partials -> final output (B, D) flat.
__global__ __launch_bounds__(256) void k4b_reduce(const float* __restrict__ P4,
                                                  float* __restrict__ out) {
  int g = blockIdx.x * 256 + threadIdx.x;     // 0..81919 == b*DD + d
  int d = g % DD;
  int b = g / DD;
  float s = 0.f;
#pragma unroll
  for (int so = 0; so < 16; ++so) s += P4[((size_t)(so * BB + b)) * DD + d];
  out[g] = s;
}

// ---------------------------------------------------------------------------
extern "C" void kernel_launch(void* const* d_in, const int* in_sizes, int n_in,
                              void* d_out, int out_size, void* d_ws, size_t ws_size,
                              hipStream_t stream) {
  const float* x       = (const float*)d_in[0];
  const float* Wssm    = (const float*)d_in[1];
  const float* Wmlp    = (const float*)d_in[2];
  const float* Wout    = (const float*)d_in[3];
  const float* conv_w  = (const float*)d_in[4];
  const float* conv_b  = (const float*)d_in[5];
  const float* conv_st = (const float*)d_in[6];
  const float* Wx      = (const float*)d_in[7];
  const float* Wdt     = (const float*)d_in[8];
  const float* dt_bias = (const float*)d_in[9];
  const float* A_log   = (const float*)d_in[10];
  const float* Dvec    = (const float*)d_in[11];
  const float* h       = (const float*)d_in[12];
  float* out = (float*)d_out;

  float* ws = (float*)d_ws;
  float* xT  = ws;                       // 81,920
  float* P1  = xT  + 81920;              // 2,621,440
  float* xt  = P1  + 2621440;            // 163,840
  float* res = xt  + 163840;             // 163,840
  float* dbc = res + 163840;             // 6,144
  float* zT  = dbc + 6144;               // 163,840
  float* P4  = zT  + 163840;             // 1,310,720  (total ~18.05 MB)

  hipLaunchKernelGGL(k0_prep,     dim3(320),  dim3(256), 0, stream, x, xT, dbc);
  hipLaunchKernelGGL(k1a_gemm_in, dim3(1280), dim3(256), 0, stream, Wssm, Wmlp, xT, P1);
  hipLaunchKernelGGL(k1b_epilogue,dim3(640),  dim3(256), 0, stream, P1, conv_st, conv_w, conv_b, xt, res);
  hipLaunchKernelGGL(k2_dbc,      dim3(192),  dim3(256), 0, stream, xt, Wx, dbc);
  hipLaunchKernelGGL(k3_ssm,      dim3(320),  dim3(256), 0, stream, dbc, Wdt, dt_bias, A_log, Dvec, h, xt, res, zT);
  hipLaunchKernelGGL(k4a_gemm_out,dim3(640),  dim3(256), 0, stream, Wout, zT, P4);
  hipLaunchKernelGGL(k4b_reduce,  dim3(320),  dim3(256), 0, stream, P4, out);
}